// Round 5
// baseline (165.053 us; speedup 1.0000x reference)
//
#include <hip/hip_runtime.h>

#define Bn 32
#define Tn 24
#define Dn 32
#define Hn 32
#define Cn 1024
#define DC (Dn*Cn)      /* 32768 */
#define TDC (Tn*Dn*Cn)  /* 786432 */
#define MP 34
#define PPXN (MP*MP)    /* 1156 */
#define IMGS (MP*MP*32) /* shorts per image */
#define SCALE 1.442695041f

typedef __attribute__((ext_vector_type(8))) short bf16x8;
typedef __attribute__((ext_vector_type(4))) float f32x4;

union U8 { unsigned u[4]; int4 i; bf16x8 v; };

__device__ __forceinline__ unsigned cvt_pk(float lo, float hi) {
    unsigned r; asm("v_cvt_pk_bf16_f32 %0, %1, %2" : "=v"(r) : "v"(lo), "v"(hi)); return r;
}
__device__ __forceinline__ float lo16f(unsigned u) { return __builtin_bit_cast(float, u << 16); }
__device__ __forceinline__ float hi16f(unsigned u) { return __builtin_bit_cast(float, u & 0xffff0000u); }
__device__ __forceinline__ float rcp_(float x) { return __builtin_amdgcn_rcpf(x); }
__device__ __forceinline__ float exp2_(float x) { return __builtin_amdgcn_exp2f(x); }

struct __align__(16) LdsL {
    unsigned short Xh[2][32][48];   // [buf][b][d pad48] hi plane (one cell)
    unsigned short Xl[2][32][48];   // lo plane
    float Hf[2][32][36];            // [buf][b][hid pad36] fp32 h
};

// ---- zero the 1-px halo ring of every (img, chunk) plane ----
__global__ __launch_bounds__(512)
void zero_halo(unsigned short* __restrict__ sp) {
    int gid = blockIdx.x * 512 + threadIdx.x;
    if (gid >= 3072 * 132) return;
    int plane = gid / 132;
    int r = gid - plane * 132;
    int m, n;
    if (r < 34)       { m = 0;      n = r; }
    else if (r < 68)  { m = 33;     n = r - 34; }
    else if (r < 100) { m = r - 67; n = 0; }
    else              { m = r - 99; n = 33; }
    int4 z = {0, 0, 0, 0};
    *(int4*)(sp + ((size_t)plane * PPXN + m * MP + n) * 8) = z;
}

// ---- LSTM: 1024 blocks x 256 thr; block = 1 cell; wave w: bh=w>>1, gh=w&1 ----
// wave computes rows bh*16..+15, gate cols qtype*32 + gh*16 + l16.
__global__ __launch_bounds__(256, 4)
void lstm_k5(const float* __restrict__ x,
             const float* __restrict__ Wih,
             const float* __restrict__ Whh,
             const float* __restrict__ bih,
             const float* __restrict__ bhh,
             unsigned short* __restrict__ sp)
{
    __shared__ LdsL lds;
    const int tid  = threadIdx.x;
    const int lane = tid & 63;
    const int wave = tid >> 6;
    const int bh   = wave >> 1;
    const int gh   = wave & 1;
    const int l16  = lane & 15;
    const int kg   = lane >> 4;
    const int bid  = blockIdx.x;
    const int cell = (bid & 7) * 128 + (bid >> 3);   // XCD-contiguous cells

    // ---- W fragments, split hi/lo via cvt_pk (pairs along k), pre-scaled ----
    U8 wihh[4], wihl[4], whhh[4], whhl[4];
    float biasr[4];
#pragma unroll
    for (int q = 0; q < 4; ++q) {
        const int g = q * 32 + gh * 16 + l16;
        const float* wp = Wih + (size_t)cell * 4096 + g * 32 + kg * 8;
        const float* hp = Whh + (size_t)cell * 4096 + g * 32 + kg * 8;
        float wv[8], hv[8];
#pragma unroll
        for (int j = 0; j < 8; ++j) { wv[j] = wp[j] * SCALE; hv[j] = hp[j] * SCALE; }
#pragma unroll
        for (int p = 0; p < 4; ++p) {
            unsigned a = cvt_pk(wv[2*p], wv[2*p+1]);
            wihh[q].u[p] = a;
            wihl[q].u[p] = cvt_pk(wv[2*p] - lo16f(a), wv[2*p+1] - hi16f(a));
            unsigned b = cvt_pk(hv[2*p], hv[2*p+1]);
            whhh[q].u[p] = b;
            whhl[q].u[p] = cvt_pk(hv[2*p] - lo16f(b), hv[2*p+1] - hi16f(b));
        }
        biasr[q] = (bih[cell * 128 + g] + bhh[cell * 128 + g]) * SCALE;
    }

    // ---- x staging map: thread -> (b=tid>>3, d0=(tid&7)*4), 4 dword gathers ----
    const int sb = tid >> 3;
    const int d0 = (tid & 7) * 4;
    const float* xg0 = x + (size_t)sb * TDC + (size_t)d0 * Cn + cell;

    // sp store base (gh==0 waves store rows bh*16+l16, chunk kg)
    const int sm = cell >> 5, sn = cell & 31;
    const int ppx = (sm + 1) * MP + (sn + 1);
    unsigned short* spb = sp + ((size_t)(bh * 16 + l16) * Tn * 4 + kg) * (PPXN * 8)
                             + (size_t)ppx * 8;

    float hD[4] = {};   // h(t-1) D-layout: rows bh*16+kg*4+r, col gh*16+l16
    float cst[4] = {};
    float nx0 = xg0[0], nx1 = xg0[Cn], nx2 = xg0[2 * Cn], nx3 = xg0[3 * Cn];

    for (int t = 0; t < Tn; ++t) {
        const int bufi = t & 1;
        // -- stage x(t): split hi/lo, b64 writes --
        {
            unsigned a0 = cvt_pk(nx0, nx1), a1 = cvt_pk(nx2, nx3);
            float r0 = nx0 - lo16f(a0), r1 = nx1 - hi16f(a0);
            float r2 = nx2 - lo16f(a1), r3 = nx3 - hi16f(a1);
            int2 hi2 = {(int)a0, (int)a1};
            int2 lo2 = {(int)cvt_pk(r0, r1), (int)cvt_pk(r2, r3)};
            *(int2*)&lds.Xh[bufi][sb][d0] = hi2;
            *(int2*)&lds.Xl[bufi][sb][d0] = lo2;
        }
        // -- write h(t-1) to Hf[bufi] --
#pragma unroll
        for (int r = 0; r < 4; ++r)
            lds.Hf[bufi][bh * 16 + kg * 4 + r][gh * 16 + l16] = hD[r];
        // -- prefetch x(t+1) --
        if (t < Tn - 1) {
            const float* xg = xg0 + (size_t)(t + 1) * DC;
            nx0 = xg[0]; nx1 = xg[Cn]; nx2 = xg[2 * Cn]; nx3 = xg[3 * Cn];
        }
        __syncthreads();

        // -- A-fragments of X (rows bh*16+l16, k=kg*8..+7) --
        U8 xfh, xfl;
        xfh.v = *(const bf16x8*)&lds.Xh[bufi][bh * 16 + l16][kg * 8];
        xfl.v = *(const bf16x8*)&lds.Xl[bufi][bh * 16 + l16][kg * 8];
        // -- A-fragments of h(t-1): fp32 -> hi/lo bf16 (cvt_pk along k) --
        U8 hfh, hfl;
        const float* hp = &lds.Hf[bufi][bh * 16 + l16][kg * 8];
        float4 ha = *(const float4*)hp;
        float4 hb = *(const float4*)(hp + 4);
        unsigned p0 = cvt_pk(ha.x, ha.y), p1 = cvt_pk(ha.z, ha.w);
        unsigned p2 = cvt_pk(hb.x, hb.y), p3 = cvt_pk(hb.z, hb.w);
        hfh.u[0] = p0; hfh.u[1] = p1; hfh.u[2] = p2; hfh.u[3] = p3;
        hfl.u[0] = cvt_pk(ha.x - lo16f(p0), ha.y - hi16f(p0));
        hfl.u[1] = cvt_pk(ha.z - lo16f(p1), ha.w - hi16f(p1));
        hfl.u[2] = cvt_pk(hb.x - lo16f(p2), hb.y - hi16f(p2));
        hfl.u[3] = cvt_pk(hb.z - lo16f(p3), hb.w - hi16f(p3));
        // -- store h(t-1) bf16-hi to sp (one gh-wave per row set) --
        if (gh == 0 && t > 0) {
            int4 sv = {(int)p0, (int)p1, (int)p2, (int)p3};
            *(int4*)(spb + (size_t)(t - 1) * IMGS) = sv;
        }

        // -- MFMA: 6-term split per gate-type tile --
        f32x4 acc[4];
#pragma unroll
        for (int q = 0; q < 4; ++q) {
            f32x4 a = {biasr[q], biasr[q], biasr[q], biasr[q]};
            a = __builtin_amdgcn_mfma_f32_16x16x32_bf16(xfh.v, wihh[q].v, a, 0, 0, 0);
            a = __builtin_amdgcn_mfma_f32_16x16x32_bf16(xfl.v, wihh[q].v, a, 0, 0, 0);
            a = __builtin_amdgcn_mfma_f32_16x16x32_bf16(xfh.v, wihl[q].v, a, 0, 0, 0);
            a = __builtin_amdgcn_mfma_f32_16x16x32_bf16(hfh.v, whhh[q].v, a, 0, 0, 0);
            a = __builtin_amdgcn_mfma_f32_16x16x32_bf16(hfl.v, whhh[q].v, a, 0, 0, 0);
            a = __builtin_amdgcn_mfma_f32_16x16x32_bf16(hfh.v, whhl[q].v, a, 0, 0, 0);
            acc[q] = a;
        }

        // -- gates (pre-scaled by log2e: exp2 direct) --
#pragma unroll
        for (int r = 0; r < 4; ++r) {
            float gi = acc[0][r], gf = acc[1][r];
            float gg = acc[2][r], go = acc[3][r];
            float ig = rcp_(1.f + exp2_(-gi));
            float fg = rcp_(1.f + exp2_(-gf));
            float gt = 1.f - 2.f * rcp_(1.f + exp2_(gg + gg));
            float og = rcp_(1.f + exp2_(-go));
            float c  = fg * cst[r] + ig * gt;
            cst[r] = c;
            float tc = 1.f - 2.f * rcp_(1.f + exp2_((2.f * SCALE) * c));
            hD[r] = og * tc;
        }
    }

    // ---- epilogue: flush h(23) ----
#pragma unroll
    for (int r = 0; r < 4; ++r)
        lds.Hf[0][bh * 16 + kg * 4 + r][gh * 16 + l16] = hD[r];
    __syncthreads();
    if (gh == 0) {
        const float* hp = &lds.Hf[0][bh * 16 + l16][kg * 8];
        float4 ha = *(const float4*)hp;
        float4 hb = *(const float4*)(hp + 4);
        int4 sv = {(int)cvt_pk(ha.x, ha.y), (int)cvt_pk(ha.z, ha.w),
                   (int)cvt_pk(hb.x, hb.y), (int)cvt_pk(hb.z, hb.w)};
        *(int4*)(spb + (size_t)(Tn - 1) * IMGS) = sv;
    }
}

// ---- conv: 768 blocks (b,t) x 512 thr, 2 px/thread, fp32 math, fused sigmoid ----
__global__ __launch_bounds__(512, 4)
void conv_k4(const unsigned short* __restrict__ sp,
             const float* __restrict__ cw,
             const float* __restrict__ cb,
             float* __restrict__ out)
{
    __shared__ float wlds[9][32];
    const int tid = threadIdx.x;
    const int img = blockIdx.x;
    if (tid < 288) wlds[tid >> 5][tid & 31] = cw[(tid & 31) * 9 + (tid >> 5)];
    __syncthreads();
    const float bias = cb[0];
    float acc[2] = {bias, bias};
    int ppx[2];
#pragma unroll
    for (int pk = 0; pk < 2; ++pk) {
        int px = tid + pk * 512;
        ppx[pk] = ((px >> 5) + 1) * MP + (px & 31) + 1;
    }
#pragma unroll
    for (int hc = 0; hc < 4; ++hc) {
        float4 wa[9], wb[9];
#pragma unroll
        for (int tap = 0; tap < 9; ++tap) {
            wa[tap] = *(const float4*)&wlds[tap][hc * 8];
            wb[tap] = *(const float4*)&wlds[tap][hc * 8 + 4];
        }
        const unsigned short* plane = sp + (size_t)(img * 4 + hc) * (PPXN * 8);
#pragma unroll
        for (int pk = 0; pk < 2; ++pk) {
            const unsigned short* base = plane + (size_t)ppx[pk] * 8;
            float a = acc[pk];
#pragma unroll
            for (int dm = -1; dm <= 1; ++dm)
#pragma unroll
                for (int dn = -1; dn <= 1; ++dn) {
                    const int tap = (dm + 1) * 3 + (dn + 1);
                    int4 v = *(const int4*)(base + (dm * MP + dn) * 8);
                    float4 w0 = wa[tap], w1 = wb[tap];
                    a = fmaf(lo16f((unsigned)v.x), w0.x, a);
                    a = fmaf(hi16f((unsigned)v.x), w0.y, a);
                    a = fmaf(lo16f((unsigned)v.y), w0.z, a);
                    a = fmaf(hi16f((unsigned)v.y), w0.w, a);
                    a = fmaf(lo16f((unsigned)v.z), w1.x, a);
                    a = fmaf(hi16f((unsigned)v.z), w1.y, a);
                    a = fmaf(lo16f((unsigned)v.w), w1.z, a);
                    a = fmaf(hi16f((unsigned)v.w), w1.w, a);
                }
            acc[pk] = a;
        }
    }
#pragma unroll
    for (int pk = 0; pk < 2; ++pk)
        out[(size_t)img * 1024 + tid + pk * 512] = rcp_(1.f + exp2_(-SCALE * acc[pk]));
}

extern "C" void kernel_launch(void* const* d_in, const int* in_sizes, int n_in,
                              void* d_out, int out_size, void* d_ws, size_t ws_size,
                              hipStream_t stream) {
    const float* x   = (const float*)d_in[0];
    const float* Wih = (const float*)d_in[1];
    const float* Whh = (const float*)d_in[2];
    const float* bih = (const float*)d_in[3];
    const float* bhh = (const float*)d_in[4];
    const float* cw  = (const float*)d_in[5];
    const float* cb  = (const float*)d_in[6];
    float* out = (float*)d_out;
    unsigned short* sp = (unsigned short*)d_ws;  // bf16 (B,T, chunk4, 34,34, 8ch)

    zero_halo<<<792, 512, 0, stream>>>(sp);
    lstm_k5<<<1024, 256, 0, stream>>>(x, Wih, Whh, bih, bhh, sp);
    conv_k4<<<Bn * Tn, 512, 0, stream>>>(sp, cw, cb, out);
}

// Round 7
// 141.039 us; speedup vs baseline: 1.1703x; 1.1703x over previous
//
#include <hip/hip_runtime.h>

#define Bn 32
#define Tn 24
#define Dn 32
#define Hn 32
#define Cn 1024
#define DC (Dn*Cn)      /* 32768 */
#define TDC (Tn*Dn*Cn)  /* 786432 */
#define MP 34
#define PPXN (MP*MP)    /* 1156 */
#define IMGS (MP*MP*32) /* shorts per image (4 planes * 1156 * 8) */
#define SCALE 1.442695041f

typedef __attribute__((ext_vector_type(8))) short bf16x8;
typedef __attribute__((ext_vector_type(4))) float f32x4;

union U8 { unsigned u[4]; int4 i; bf16x8 v; };

__device__ __forceinline__ unsigned cvt_pk(float lo, float hi) {
    unsigned r; asm("v_cvt_pk_bf16_f32 %0, %1, %2" : "=v"(r) : "v"(lo), "v"(hi)); return r;
}
__device__ __forceinline__ float lo16f(unsigned u) { return __builtin_bit_cast(float, u << 16); }
__device__ __forceinline__ float hi16f(unsigned u) { return __builtin_bit_cast(float, u & 0xffff0000u); }
__device__ __forceinline__ float rcp_(float x) { return __builtin_amdgcn_rcpf(x); }
__device__ __forceinline__ float exp2_(float x) { return __builtin_amdgcn_exp2f(x); }

__device__ __forceinline__ void gload_lds(const float* g, float* l) {
    __builtin_amdgcn_global_load_lds(
        (const __attribute__((address_space(1))) unsigned int*)g,
        (__attribute__((address_space(3))) unsigned int*)l, 4, 0, 0);
}

struct __align__(16) LdsL {
    // X slot s = b*160 + dslot*5 + c  (c==4 is pad; stored d = dslot ^ (b&7))
    float X[2][2560];
    float H[2][4][16][33];   // [buf][cell][b][hid pad33] fp32
};

// ---- zero the 1-px halo ring of every (img, chunk) plane ----
__global__ __launch_bounds__(512)
void zero_halo(unsigned short* __restrict__ sp) {
    int gid = blockIdx.x * 512 + threadIdx.x;
    if (gid >= 3072 * 132) return;
    int plane = gid / 132;
    int r = gid - plane * 132;
    int m, n;
    if (r < 34)       { m = 0;      n = r; }
    else if (r < 68)  { m = 33;     n = r - 34; }
    else if (r < 100) { m = r - 67; n = 0; }
    else              { m = r - 99; n = 33; }
    int4 z = {0, 0, 0, 0};
    *(int4*)(sp + ((size_t)plane * PPXN + m * MP + n) * 8) = z;
}

// ---- LSTM: grid 512 = (cellgroup 256) x (bslice 2); 512 thr = 8 waves ----
// wave w: cell ci = w>>1, col-half gh = w&1. Block: cells cg*4..+3, batch bslice*16..+15.
__global__ __launch_bounds__(512, 4)
void lstm_k7(const float* __restrict__ x,
             const float* __restrict__ Wih,
             const float* __restrict__ Whh,
             const float* __restrict__ bih,
             const float* __restrict__ bhh,
             unsigned short* __restrict__ sp)
{
    __shared__ LdsL lds;
    const int tid  = threadIdx.x;
    const int lane = tid & 63;
    const int wave = tid >> 6;
    const int ci   = wave >> 1;
    const int gh   = wave & 1;
    const int l16  = lane & 15;
    const int kg   = lane >> 4;
    const int bid  = blockIdx.x;
    const int u    = bid >> 3, xcd = bid & 7;
    const int cg   = xcd * 32 + (u & 31);          // XCD-contiguous cell groups
    const int bslice = u >> 5;
    const int cellbase = cg * 4;
    const int cell = cellbase + ci;
    const int gb0  = bslice * 16;

    // ---- W fragments, split hi/lo via cvt_pk (pairs along k), pre-scaled ----
    U8 wihh[4], wihl[4], whhh[4], whhl[4];
    float biasr[4];
#pragma unroll
    for (int q = 0; q < 4; ++q) {
        const int g = q * 32 + gh * 16 + l16;
        const float* wp = Wih + (size_t)cell * 4096 + g * 32 + kg * 8;
        const float* hp = Whh + (size_t)cell * 4096 + g * 32 + kg * 8;
        float wv[8], hv[8];
#pragma unroll
        for (int j = 0; j < 8; ++j) { wv[j] = wp[j] * SCALE; hv[j] = hp[j] * SCALE; }
#pragma unroll
        for (int p = 0; p < 4; ++p) {
            unsigned a = cvt_pk(wv[2*p], wv[2*p+1]);
            wihh[q].u[p] = a;
            wihl[q].u[p] = cvt_pk(wv[2*p] - lo16f(a), wv[2*p+1] - hi16f(a));
            unsigned b = cvt_pk(hv[2*p], hv[2*p+1]);
            whhh[q].u[p] = b;
            whhl[q].u[p] = cvt_pk(hv[2*p] - lo16f(b), hv[2*p+1] - hi16f(b));
        }
        biasr[q] = (bih[cell * 128 + g] + bhh[cell * 128 + g]) * SCALE;
    }

    // ---- x stage slots: slot s = tid + k*512 -> (c=s%5, dslot=(s/5)&31, b=(s/5)>>5)
    // LDS index IS s (linear: wave-uniform base + lane*4). Stored d = dslot ^ (b&7)
    // (bank-spread swizzle applied on the GLOBAL address side; LDS stays linear).
    const float* gp[5];
#pragma unroll
    for (int k = 0; k < 5; ++k) {
        int s = tid + k * 512;
        int c = s % 5; int g = s / 5;
        int dslot = g & 31; int b = g >> 5;
        int dd = dslot ^ (b & 7);
        if (c > 3) c = 3;                          // pad lane: duplicate load
        gp[k] = x + (size_t)(gb0 + b) * TDC + (size_t)dd * Cn + cellbase + c;
    }
    // issue x(0) -> X[0]
#pragma unroll
    for (int k = 0; k < 5; ++k)
        gload_lds(gp[k], &lds.X[0][k * 512 + wave * 64]);

    // ---- sp store map (gh==0 waves): lane -> (b_loc=lane>>2, chunk kg2=lane&3) ----
    const int b_loc = lane >> 2, kg2 = lane & 3;
    const int sm = cell >> 5, sn = cell & 31;
    const int ppx = (sm + 1) * MP + (sn + 1);
    unsigned short* spb = sp + (((size_t)(gb0 + b_loc) * (Tn * 4) + kg2) * PPXN + ppx) * 8;

    float hD[4] = {}, cst[4] = {};

    for (int t = 0; t < Tn; ++t) {
        const int p = t & 1;
        // -- A: write h(t-1) (zeros at t=0) -> H[p] --
#pragma unroll
        for (int r = 0; r < 4; ++r)
            lds.H[p][ci][kg * 4 + r][gh * 16 + l16] = hD[r];
        __syncthreads();   // drains x(t) async loads; H[p] visible

        // -- C: issue x(t+1) -> X[1-p] (lands by next barrier) --
        if (t + 1 < Tn) {
#pragma unroll
            for (int k = 0; k < 5; ++k)
                gload_lds(gp[k] + (size_t)(t + 1) * DC, &lds.X[1 - p][k * 512 + wave * 64]);
        }

        // -- D: store h(t-1) bf16-hi to sp (gh==0 waves) --
        if (gh == 0 && t > 0) {
            float e[8];
#pragma unroll
            for (int j = 0; j < 8; ++j) e[j] = lds.H[p][ci][b_loc][kg2 * 8 + j];
            int4 sv = {(int)cvt_pk(e[0], e[1]), (int)cvt_pk(e[2], e[3]),
                       (int)cvt_pk(e[4], e[5]), (int)cvt_pk(e[6], e[7])};
            *(int4*)(spb + (size_t)(t - 1) * IMGS) = sv;
        }

        // -- E: fragments --
        U8 xfh, xfl, hfh, hfl;
        {
            float e[8];
#pragma unroll
            for (int j = 0; j < 8; ++j)
                e[j] = lds.X[p][l16 * 160 + ((kg * 8 + j) ^ (l16 & 7)) * 5 + ci];
#pragma unroll
            for (int pp = 0; pp < 4; ++pp) {
                unsigned a = cvt_pk(e[2*pp], e[2*pp+1]);
                xfh.u[pp] = a;
                xfl.u[pp] = cvt_pk(e[2*pp] - lo16f(a), e[2*pp+1] - hi16f(a));
            }
#pragma unroll
            for (int j = 0; j < 8; ++j)
                e[j] = lds.H[p][ci][l16][kg * 8 + j];
#pragma unroll
            for (int pp = 0; pp < 4; ++pp) {
                unsigned a = cvt_pk(e[2*pp], e[2*pp+1]);
                hfh.u[pp] = a;
                hfl.u[pp] = cvt_pk(e[2*pp] - lo16f(a), e[2*pp+1] - hi16f(a));
            }
        }

        // -- F: MFMA, 6-term split per q-tile --
        f32x4 acc[4];
#pragma unroll
        for (int q = 0; q < 4; ++q) {
            f32x4 a = {biasr[q], biasr[q], biasr[q], biasr[q]};
            a = __builtin_amdgcn_mfma_f32_16x16x32_bf16(xfh.v, wihh[q].v, a, 0, 0, 0);
            a = __builtin_amdgcn_mfma_f32_16x16x32_bf16(xfl.v, wihh[q].v, a, 0, 0, 0);
            a = __builtin_amdgcn_mfma_f32_16x16x32_bf16(xfh.v, wihl[q].v, a, 0, 0, 0);
            a = __builtin_amdgcn_mfma_f32_16x16x32_bf16(hfh.v, whhh[q].v, a, 0, 0, 0);
            a = __builtin_amdgcn_mfma_f32_16x16x32_bf16(hfl.v, whhh[q].v, a, 0, 0, 0);
            a = __builtin_amdgcn_mfma_f32_16x16x32_bf16(hfh.v, whhl[q].v, a, 0, 0, 0);
            acc[q] = a;
        }

        // -- G: gates (pre-scaled by log2e), rows b = kg*4+r, hid col gh*16+l16 --
#pragma unroll
        for (int r = 0; r < 4; ++r) {
            float gi = acc[0][r], gf = acc[1][r];
            float gg = acc[2][r], go = acc[3][r];
            float ig = rcp_(1.f + exp2_(-gi));
            float fg = rcp_(1.f + exp2_(-gf));
            float gt = 1.f - 2.f * rcp_(1.f + exp2_(gg + gg));
            float og = rcp_(1.f + exp2_(-go));
            float c  = fg * cst[r] + ig * gt;
            cst[r] = c;
            float tc = 1.f - 2.f * rcp_(1.f + exp2_((2.f * SCALE) * c));
            hD[r] = og * tc;
        }
    }

    // ---- epilogue: flush h(Tn-1) ----
#pragma unroll
    for (int r = 0; r < 4; ++r)
        lds.H[0][ci][kg * 4 + r][gh * 16 + l16] = hD[r];
    __syncthreads();
    if (gh == 0) {
        float e[8];
#pragma unroll
        for (int j = 0; j < 8; ++j) e[j] = lds.H[0][ci][b_loc][kg2 * 8 + j];
        int4 sv = {(int)cvt_pk(e[0], e[1]), (int)cvt_pk(e[2], e[3]),
                   (int)cvt_pk(e[4], e[5]), (int)cvt_pk(e[6], e[7])};
        *(int4*)(spb + (size_t)(Tn - 1) * IMGS) = sv;
    }
}

// ---- conv: 768 blocks (b,t) x 512 thr, 2 px/thread, fp32 math, fused sigmoid ----
__global__ __launch_bounds__(512, 4)
void conv_k4(const unsigned short* __restrict__ sp,
             const float* __restrict__ cw,
             const float* __restrict__ cb,
             float* __restrict__ out)
{
    __shared__ float wlds[9][32];
    const int tid = threadIdx.x;
    const int img = blockIdx.x;
    if (tid < 288) wlds[tid >> 5][tid & 31] = cw[(tid & 31) * 9 + (tid >> 5)];
    __syncthreads();
    const float bias = cb[0];
    float acc[2] = {bias, bias};
    int ppx[2];
#pragma unroll
    for (int pk = 0; pk < 2; ++pk) {
        int px = tid + pk * 512;
        ppx[pk] = ((px >> 5) + 1) * MP + (px & 31) + 1;
    }
#pragma unroll
    for (int hc = 0; hc < 4; ++hc) {
        float4 wa[9], wb[9];
#pragma unroll
        for (int tap = 0; tap < 9; ++tap) {
            wa[tap] = *(const float4*)&wlds[tap][hc * 8];
            wb[tap] = *(const float4*)&wlds[tap][hc * 8 + 4];
        }
        const unsigned short* plane = sp + (size_t)(img * 4 + hc) * (PPXN * 8);
#pragma unroll
        for (int pk = 0; pk < 2; ++pk) {
            const unsigned short* base = plane + (size_t)ppx[pk] * 8;
            float a = acc[pk];
#pragma unroll
            for (int dm = -1; dm <= 1; ++dm)
#pragma unroll
                for (int dn = -1; dn <= 1; ++dn) {
                    const int tap = (dm + 1) * 3 + (dn + 1);
                    int4 v = *(const int4*)(base + (dm * MP + dn) * 8);
                    float4 w0 = wa[tap], w1 = wb[tap];
                    a = fmaf(lo16f((unsigned)v.x), w0.x, a);
                    a = fmaf(hi16f((unsigned)v.x), w0.y, a);
                    a = fmaf(lo16f((unsigned)v.y), w0.z, a);
                    a = fmaf(hi16f((unsigned)v.y), w0.w, a);
                    a = fmaf(lo16f((unsigned)v.z), w1.x, a);
                    a = fmaf(hi16f((unsigned)v.z), w1.y, a);
                    a = fmaf(lo16f((unsigned)v.w), w1.z, a);
                    a = fmaf(hi16f((unsigned)v.w), w1.w, a);
                }
            acc[pk] = a;
        }
    }
#pragma unroll
    for (int pk = 0; pk < 2; ++pk)
        out[(size_t)img * 1024 + tid + pk * 512] = rcp_(1.f + exp2_(-SCALE * acc[pk]));
}

extern "C" void kernel_launch(void* const* d_in, const int* in_sizes, int n_in,
                              void* d_out, int out_size, void* d_ws, size_t ws_size,
                              hipStream_t stream) {
    const float* x   = (const float*)d_in[0];
    const float* Wih = (const float*)d_in[1];
    const float* Whh = (const float*)d_in[2];
    const float* bih = (const float*)d_in[3];
    const float* bhh = (const float*)d_in[4];
    const float* cw  = (const float*)d_in[5];
    const float* cb  = (const float*)d_in[6];
    float* out = (float*)d_out;
    unsigned short* sp = (unsigned short*)d_ws;  // bf16 (B,T, chunk4, 34,34, 8ch)

    zero_halo<<<792, 512, 0, stream>>>(sp);
    lstm_k7<<<512, 512, 0, stream>>>(x, Wih, Whh, bih, bhh, sp);
    conv_k4<<<Bn * Tn, 512, 0, stream>>>(sp, cw, cb, out);
}